// Round 6
// baseline (183.452 us; speedup 1.0000x reference)
//
#include <hip/hip_runtime.h>
#include <math.h>

#define NROWS 4096
#define VCOLS 32000
#define NV4   (VCOLS / 4)     // 8000 float4 per row
#define NBMW  1000            // bitmap words (32000 bits)

typedef float f32x4 __attribute__((ext_vector_type(4)));

// Constants from reference: LS=0.1, CONF=0.9, SM=0.1/31999
constexpr float CONF_F   = 0.9f;
constexpr float SM_F     = 0.1f / 31999.0f;          // 3.1250977e-06
constexpr float KL_CONST = -1.36242896f;             // 0.9*ln(0.9) + 0.1*ln(SM)
constexpr float COEF_T   = CONF_F - SM_F;            // weight on logp[target]

// ---- kernel 1: init first-occurrence table + bitmap ----
__global__ void k_init(int* __restrict__ ft32, unsigned* __restrict__ bm) {
    int v = blockIdx.x * blockDim.x + threadIdx.x;
    if (v < VCOLS) ft32[v] = NROWS;     // sentinel: never a candidate
    if (v < NBMW)  bm[v]   = 0u;
}

// ---- kernel 2: first occurrence via atomicMin + bitmap mark ----
__global__ void k_scatter(const int* __restrict__ target,
                          int* __restrict__ ft32,
                          unsigned* __restrict__ bm,
                          int* __restrict__ tclean) {
    int j = blockIdx.x * blockDim.x + threadIdx.x;
    if (j < NROWS) {
        int t  = target[j];
        int tc = (t != -1) ? t : 0;     // tgt = where(valid, target, PAD)
        tclean[j] = tc;
        // token 0 (PAD) excluded from neg targets (neg[:,0]=0): never mark.
        if (tc != 0) {
            atomicMin(&ft32[tc], j);
            atomicOr(&bm[tc >> 5], 1u << (tc & 31));
        }
    }
}

// ---- kernel 3: fused single-pass row kernel ----
// One block per row, one coalesced nontemporal sweep of the row:
//  - online softmax stats (m, Z) + sum of logits
//  - candidate logits -> deterministic LDS slot cand[ft32[v]]
//    (filter: 4 KB L1-resident bitmap; positional lookup only on bit hits)
// Gold logit loaded once per block. Then logZ reduction, KL term,
// unlikelihood tail over the LDS candidate list.
__global__ __launch_bounds__(256, 6)
void k_main(const float* __restrict__ X,
            const int*   __restrict__ target,
            const int*   __restrict__ tclean,
            const int*   __restrict__ ft32,
            const unsigned* __restrict__ bm,
            float* __restrict__ kl_rows,
            float* __restrict__ custom_rows) {
    const int i   = blockIdx.x;
    const int tid = threadIdx.x;

    __shared__ float cand[NROWS];       // candidate logits by first-occ pos (16 KB)
    __shared__ float rm[256], rz[256], rs[256];
    __shared__ float s_logZ, s_xt;

    const bool valid = (target[i] != -1);
    if (!valid) {
        if (tid == 0) { kl_rows[i] = 0.0f; custom_rows[i] = 0.0f; }
        return;
    }

    const int    mytgt = tclean[i];
    const float* row   = X + (size_t)i * VCOLS;

    if (tid == 0) s_xt = row[mytgt];                // gold logit, once
    for (int j = tid; j < i; j += 256) cand[j] = -INFINITY;
    __syncthreads();

    const f32x4* row4 = (const f32x4*)row;          // 16B aligned (stride 128000B)
    float m = -INFINITY, Z = 0.0f, sx = 0.0f;

#define SLOT(ee_) do {                                                        \
        const int e_ = (ee_);                                                 \
        f32x4 x_ = __builtin_nontemporal_load(&row4[e_]);                     \
        unsigned nib_ = (bm[e_ >> 3] >> ((e_ & 7) * 4)) & 0xFu;               \
        float m4_ = fmaxf(fmaxf(x_.x, x_.y), fmaxf(x_.z, x_.w));              \
        if (m4_ > m) { Z *= __expf(m - m4_); m = m4_; }     /* rare */        \
        Z += __expf(x_.x - m) + __expf(x_.y - m)                              \
           + __expf(x_.z - m) + __expf(x_.w - m);                             \
        sx += (x_.x + x_.y) + (x_.z + x_.w);                                  \
        if (nib_) {                                                           \
            int b_ = e_ * 4;                                                  \
            if (nib_ & 1u) { int p_ = ft32[b_    ];                           \
                if (p_ < i && b_     != mytgt) cand[p_] = x_.x; }             \
            if (nib_ & 2u) { int p_ = ft32[b_ + 1];                           \
                if (p_ < i && b_ + 1 != mytgt) cand[p_] = x_.y; }             \
            if (nib_ & 4u) { int p_ = ft32[b_ + 2];                           \
                if (p_ < i && b_ + 2 != mytgt) cand[p_] = x_.z; }             \
            if (nib_ & 8u) { int p_ = ft32[b_ + 3];                           \
                if (p_ < i && b_ + 3 != mytgt) cand[p_] = x_.w; }             \
        }                                                                     \
    } while (0)

    int e = tid;
    while (e + 256 < NV4) { SLOT(e); SLOT(e + 256); e += 512; }
    if (e < NV4) SLOT(e);
#undef SLOT

    rm[tid] = m; rz[tid] = Z; rs[tid] = sx;
    __syncthreads();
    for (int s = 128; s > 0; s >>= 1) {
        if (tid < s) {
            float m2 = rm[tid + s], z2 = rz[tid + s];
            float mm = fmaxf(rm[tid], m2);
            rz[tid]  = rz[tid] * __expf(rm[tid] - mm) + z2 * __expf(m2 - mm);
            rm[tid]  = mm;
            rs[tid] += rs[tid + s];
        }
        __syncthreads();
    }
    if (tid == 0) {
        float logZ    = rm[0] + __logf(rz[0]);
        s_logZ        = logZ;
        float logp_t  = s_xt - logZ;
        float sumlogp = rs[0] - (float)VCOLS * logZ;   // sum_j logp[i,j]
        kl_rows[i] = KL_CONST - COEF_T * logp_t - SM_F * sumlogp;
    }
    __syncthreads();
    const float logZ = s_logZ;

    // ---- unlikelihood tail over the candidate list ----
    float acc = 0.0f;
    for (int j = tid; j < i; j += 256) {
        float xv = cand[j];                 // -inf -> p=0 -> term 0
        float p  = __expf(xv - logZ);
        float om = fmaxf(1.0f - p, 1e-5f);
        acc -= __logf(om);
    }
    rs[tid] = acc;
    __syncthreads();
    for (int s = 128; s > 0; s >>= 1) {
        if (tid < s) rs[tid] += rs[tid + s];
        __syncthreads();
    }
    if (tid == 0) custom_rows[i] = rs[0];
}

// ---- kernel 4: deterministic final reduction (1024 threads, 4 rounds) ----
__global__ __launch_bounds__(1024)
void k_final(const float* __restrict__ kl_rows,
             const float* __restrict__ custom_rows,
             const int*   __restrict__ target,
             float* __restrict__ out) {
    __shared__ float sl[1024], sc[1024], sn[1024];
    int tid = threadIdx.x;
    float L = 0.0f, C = 0.0f, Nn = 0.0f;
    for (int j = tid; j < NROWS; j += 1024) {
        L += kl_rows[j];
        C += custom_rows[j];
        int t = target[j];
        if (t != -1 && t != 0) Nn += 1.0f;    // valid & (tgt != PAD)
    }
    sl[tid] = L; sc[tid] = C; sn[tid] = Nn;
    __syncthreads();
    for (int s = 512; s > 0; s >>= 1) {
        if (tid < s) { sl[tid] += sl[tid+s]; sc[tid] += sc[tid+s]; sn[tid] += sn[tid+s]; }
        __syncthreads();
    }
    if (tid == 0) {
        float norm = sn[0];
        out[0] = sl[0] / norm + 0.1f * sc[0] / norm;
    }
}

extern "C" void kernel_launch(void* const* d_in, const int* in_sizes, int n_in,
                              void* d_out, int out_size, void* d_ws, size_t ws_size,
                              hipStream_t stream) {
    const float* X      = (const float*)d_in[0];   // (N, V) float32
    const int*   target = (const int*)d_in[1];     // (N,)   int32
    float*       out    = (float*)d_out;

    char* ws = (char*)d_ws;
    int*      ft32        = (int*)     (ws);                         // 128000 B
    unsigned* bm          = (unsigned*)(ws + 128000);                //   4096 B
    int*      tclean      = (int*)     (ws + 132096);                //  16384 B
    float*    kl_rows     = (float*)   (ws + 132096 + 16384);        //  16384 B
    float*    custom_rows = (float*)   (ws + 132096 + 32768);        //  16384 B

    k_init   <<<(VCOLS + 255) / 256, 256, 0, stream>>>(ft32, bm);
    k_scatter<<<(NROWS + 255) / 256, 256, 0, stream>>>(target, ft32, bm, tclean);
    k_main   <<<NROWS,               256, 0, stream>>>(X, target, tclean, ft32, bm,
                                                       kl_rows, custom_rows);
    k_final  <<<1,                  1024, 0, stream>>>(kl_rows, custom_rows, target, out);
}

// Round 7
// 123.860 us; speedup vs baseline: 1.4811x; 1.4811x over previous
//
#include <hip/hip_runtime.h>
#include <math.h>

#define NROWS 4096
#define VCOLS 32000
#define NV4   (VCOLS / 4)     // 8000 float4 per row

typedef float f32x4 __attribute__((ext_vector_type(4)));

// Constants from reference: LS=0.1, CONF=0.9, SM=0.1/31999
constexpr float CONF_F   = 0.9f;
constexpr float SM_F     = 0.1f / 31999.0f;          // 3.1250977e-06
constexpr float KL_CONST = -1.36242896f;             // 0.9*ln(0.9) + 0.1*ln(SM)
constexpr float COEF_T   = CONF_F - SM_F;            // weight on logp[target]

// ---- kernel 1: init first-occurrence table ----
__global__ void k_init(int* __restrict__ ft32) {
    int v = blockIdx.x * blockDim.x + threadIdx.x;
    if (v < VCOLS) ft32[v] = NROWS;     // sentinel: never a candidate
}

// ---- kernel 2: first occurrence via atomicMin ----
__global__ void k_scatter(const int* __restrict__ target,
                          int* __restrict__ ft32) {
    int j = blockIdx.x * blockDim.x + threadIdx.x;
    if (j < NROWS) {
        int t  = target[j];
        int tc = (t != -1) ? t : 0;     // tgt = where(valid, target, PAD)
        // token 0 (PAD) excluded from neg targets (neg[:,0]=0): never mark.
        if (tc != 0) atomicMin(&ft32[tc], j);
    }
}

// ---- kernel 3: pack table to u16 (values <= 4096) ----
__global__ void k_pack(const int* __restrict__ ft32,
                       unsigned short* __restrict__ ft16) {
    int v = blockIdx.x * blockDim.x + threadIdx.x;
    if (v < VCOLS) ft16[v] = (unsigned short)ft32[v];
}

// ---- kernel 4: fused single-pass row kernel (1024 threads/row) ----
// One block per row, one coalesced sweep: branchless online softmax stats
// + sum of logits + candidate logits into deterministic LDS slots
// cand[ft16[v]] (candidate iff ft16[v] < i, v != tgt_i; ft16[0]==NROWS).
// 1024-thread blocks -> 2 resident blocks/CU -> 512 fat HBM streams.
__global__ __launch_bounds__(1024)
void k_main(const float* __restrict__ X,
            const int*   __restrict__ target,
            const unsigned short* __restrict__ ft16,
            float* __restrict__ kl_rows,
            float* __restrict__ custom_rows) {
    const int i   = blockIdx.x;
    const int tid = threadIdx.x;

    __shared__ float cand[NROWS];                   // 16 KB
    __shared__ float rm[1024], rz[1024], rs[1024];  // 12 KB
    __shared__ float s_logZ, s_xt;

    const int t = target[i];
    if (t == -1) {
        if (tid == 0) { kl_rows[i] = 0.0f; custom_rows[i] = 0.0f; }
        return;
    }
    const int    mytgt = t;          // valid -> tclean == target
    const float* row   = X + (size_t)i * VCOLS;

    if (tid == 0) s_xt = row[mytgt];                // gold logit, once
    for (int j = tid; j < i; j += 1024) cand[j] = -INFINITY;
    __syncthreads();

    const f32x4* row4 = (const f32x4*)row;          // 16B aligned (stride 128000B)
    const int2*  ft2  = (const int2*)ft16;          // 4 u16 per float4

    float m = -INFINITY, Z = 0.0f, sx = 0.0f;

#define SLOT(ee_) do {                                                        \
        const int e_ = (ee_);                                                 \
        f32x4 x_ = row4[e_];                                                  \
        int2  f_ = ft2[e_];                                                   \
        float m4_ = fmaxf(fmaxf(x_.x, x_.y), fmaxf(x_.z, x_.w));              \
        float mn_ = fmaxf(m, m4_);                                            \
        Z = Z * __expf(m - mn_)                                               \
          + __expf(x_.x - mn_) + __expf(x_.y - mn_)                           \
          + __expf(x_.z - mn_) + __expf(x_.w - mn_);                          \
        m = mn_;                                                              \
        sx += (x_.x + x_.y) + (x_.z + x_.w);                                  \
        int b_  = e_ * 4;                                                     \
        int a0_ = f_.x & 0xFFFF, a1_ = (int)(((unsigned)f_.x) >> 16);         \
        int a2_ = f_.y & 0xFFFF, a3_ = (int)(((unsigned)f_.y) >> 16);         \
        if (a0_ < i && b_     != mytgt) cand[a0_] = x_.x;                     \
        if (a1_ < i && b_ + 1 != mytgt) cand[a1_] = x_.y;                     \
        if (a2_ < i && b_ + 2 != mytgt) cand[a2_] = x_.z;                     \
        if (a3_ < i && b_ + 3 != mytgt) cand[a3_] = x_.w;                     \
    } while (0)

    int e = tid;
    while (e + 1024 < NV4) { SLOT(e); SLOT(e + 1024); e += 2048; }
    if (e < NV4) SLOT(e);
#undef SLOT

    rm[tid] = m; rz[tid] = Z; rs[tid] = sx;
    __syncthreads();
    for (int s = 512; s > 0; s >>= 1) {
        if (tid < s) {
            float m2 = rm[tid + s], z2 = rz[tid + s];
            float mm = fmaxf(rm[tid], m2);
            rz[tid]  = rz[tid] * __expf(rm[tid] - mm) + z2 * __expf(m2 - mm);
            rm[tid]  = mm;
            rs[tid] += rs[tid + s];
        }
        __syncthreads();
    }
    if (tid == 0) {
        float logZ    = rm[0] + __logf(rz[0]);
        s_logZ        = logZ;
        float logp_t  = s_xt - logZ;
        float sumlogp = rs[0] - (float)VCOLS * logZ;   // sum_j logp[i,j]
        kl_rows[i] = KL_CONST - COEF_T * logp_t - SM_F * sumlogp;
    }
    __syncthreads();
    const float logZ = s_logZ;

    // ---- unlikelihood tail over the candidate list ----
    float acc = 0.0f;
    for (int j = tid; j < i; j += 1024) {
        float xv = cand[j];                 // -inf -> p=0 -> term 0
        float p  = __expf(xv - logZ);
        float om = fmaxf(1.0f - p, 1e-5f);
        acc -= __logf(om);
    }
    rs[tid] = acc;
    __syncthreads();
    for (int s = 512; s > 0; s >>= 1) {
        if (tid < s) rs[tid] += rs[tid + s];
        __syncthreads();
    }
    if (tid == 0) custom_rows[i] = rs[0];
}

// ---- kernel 5: deterministic final reduction (1024 threads) ----
__global__ __launch_bounds__(1024)
void k_final(const float* __restrict__ kl_rows,
             const float* __restrict__ custom_rows,
             const int*   __restrict__ target,
             float* __restrict__ out) {
    __shared__ float sl[1024], sc[1024], sn[1024];
    int tid = threadIdx.x;
    float L = 0.0f, C = 0.0f, Nn = 0.0f;
    for (int j = tid; j < NROWS; j += 1024) {
        L += kl_rows[j];
        C += custom_rows[j];
        int t = target[j];
        if (t != -1 && t != 0) Nn += 1.0f;    // valid & (tgt != PAD)
    }
    sl[tid] = L; sc[tid] = C; sn[tid] = Nn;
    __syncthreads();
    for (int s = 512; s > 0; s >>= 1) {
        if (tid < s) { sl[tid] += sl[tid+s]; sc[tid] += sc[tid+s]; sn[tid] += sn[tid+s]; }
        __syncthreads();
    }
    if (tid == 0) {
        float norm = sn[0];
        out[0] = sl[0] / norm + 0.1f * sc[0] / norm;
    }
}

extern "C" void kernel_launch(void* const* d_in, const int* in_sizes, int n_in,
                              void* d_out, int out_size, void* d_ws, size_t ws_size,
                              hipStream_t stream) {
    const float* X      = (const float*)d_in[0];   // (N, V) float32
    const int*   target = (const int*)d_in[1];     // (N,)   int32
    float*       out    = (float*)d_out;

    char* ws = (char*)d_ws;
    int*            ft32        = (int*)           (ws);                    // 128000 B
    unsigned short* ft16        = (unsigned short*)(ws + 128000);           //  64000 B
    float*          kl_rows     = (float*)         (ws + 192000);           //  16384 B
    float*          custom_rows = (float*)         (ws + 192000 + 16384);   //  16384 B

    k_init   <<<(VCOLS + 255) / 256, 256, 0, stream>>>(ft32);
    k_scatter<<<(NROWS + 255) / 256, 256, 0, stream>>>(target, ft32);
    k_pack   <<<(VCOLS + 255) / 256, 256, 0, stream>>>(ft32, ft16);
    k_main   <<<NROWS,              1024, 0, stream>>>(X, target, ft16,
                                                       kl_rows, custom_rows);
    k_final  <<<1,                  1024, 0, stream>>>(kl_rows, custom_rows, target, out);
}